// Round 6
// baseline (442.433 us; speedup 1.0000x reference)
//
#include <hip/hip_runtime.h>

// HMM forward scan, one workgroup per unit u. U=256, N=64, S=4, B=64, T=1024.
// Wave w owns batches [16w,16w+16); lane (q=lane>>4,l=lane&15) owns batch
// b=16w+l and the 16 states j = sig(jt, 4q+r).
//
// sig() row permutation: lane's MFMA C-layout accumulator values are exactly
// its own next-step B-operand k-slices -> no LDS round-trip in the T-loop.
// E via MFMA (K=4 zero-padded). ss via 3 parallel shfl_xor (R4-proven; R5
// showed the ones-MFMA variant is slower).
//
// R6: the per-iteration exec-masked global store of ll was on the recurrence
// strand via vmcnt (stores share the counter with the x loads; scattered
// 16-line store-acks serialized each step). Now each lane captures ll into an
// 8-deep VGPR ring (lane q captures t8-octet q) and the wave flushes 8 bulk
// stores every 32 steps. Per-iter vmem = 1 load. Also: R-MFMA split into two
// independent accumulators + VALU add (one less MFMA latency on the strand).
//
// Normalization (R4 scheme, proven): Ev_{t+1} packed with rs_{t-1};
// magnitude recurrence z^2-z+1 (unit circle, bounded). Exact ll:
// ll_t = ll_{t-1} + sigma_t - sigma_{t-1} + sigma_{t-2}, sigma=log(ss).

#define U_ 256
#define N_ 64
#define S_ 4
#define B_ 64
#define T_ 1024
#define ROWP 72

typedef __attribute__((ext_vector_type(8))) __bf16 bf16x8;
typedef __attribute__((ext_vector_type(4))) float floatx4;

__device__ __forceinline__ int sig(int jt, int m) {
    return 32 * (jt >> 1) + 4 * (jt & 1) + 8 * (m >> 2) + (m & 3);
}

__launch_bounds__(256, 1)
__global__ void hmm_fwd_kernel(const float* __restrict__ xg,     // [B][T][S]
                               const float* __restrict__ trans,  // [U][N][N]
                               const float* __restrict__ emis,   // [U][N][S]
                               const float* __restrict__ initk,  // [U][N]
                               float* __restrict__ out)          // [B][T][U]
{
    __shared__ __bf16 AT[N_ * ROWP];
    __shared__ float BemS[N_][S_];
    __shared__ float IS[N_];

    const int bid = blockIdx.x;
    const int u = ((bid & 7) << 5) | (bid >> 3);   // XCD-aware u swizzle
    const int tid = threadIdx.x;
    const int lane = tid & 63;
    const int w = tid >> 6;
    const int q = lane >> 4;
    const int l = lane & 15;

    // ---------------- prologue: softmaxes (one-time) ----------------
    if (tid < 64) {
        const float* rowp = trans + (u * N_ + tid) * N_;
        float v[N_];
        #pragma unroll
        for (int k = 0; k < 16; ++k) {
            floatx4 t4 = *(const floatx4*)(rowp + 4 * k);
            v[4*k] = t4.x; v[4*k+1] = t4.y; v[4*k+2] = t4.z; v[4*k+3] = t4.w;
        }
        float m = v[0];
        #pragma unroll
        for (int j = 1; j < N_; ++j) m = fmaxf(m, v[j]);
        float s = 0.f;
        #pragma unroll
        for (int j = 0; j < N_; ++j) { v[j] = __expf(v[j] - m); s += v[j]; }
        float inv = 1.0f / s;
        #pragma unroll
        for (int j = 0; j < N_; ++j) AT[j * ROWP + tid] = (__bf16)(v[j] * inv);
    } else if (tid < 128) {
        int n = tid - 64;
        floatx4 e4 = *(const floatx4*)(emis + (u * N_ + n) * S_);
        float m = fmaxf(fmaxf(e4.x, e4.y), fmaxf(e4.z, e4.w));
        float a = __expf(e4.x - m), b2 = __expf(e4.y - m);
        float c = __expf(e4.z - m), d = __expf(e4.w - m);
        float inv = 1.0f / (a + b2 + c + d);
        BemS[n][0] = a*inv; BemS[n][1] = b2*inv; BemS[n][2] = c*inv; BemS[n][3] = d*inv;
    } else if (tid < 192) {
        int j = tid - 128;
        float v = initk[u * N_ + j];
        float m = v;
        #pragma unroll
        for (int s = 1; s < 64; s <<= 1) m = fmaxf(m, __shfl_xor(m, s, 64));
        float e = __expf(v - m);
        float ssum = e;
        #pragma unroll
        for (int s = 1; s < 64; s <<= 1) ssum += __shfl_xor(ssum, s, 64);
        IS[j] = e / ssum;
    }
    __syncthreads();

    // ------------- persistent register state -------------
    bf16x8 afrag[4][2];
    #pragma unroll
    for (int jt = 0; jt < 4; ++jt)
        #pragma unroll
        for (int kt = 0; kt < 2; ++kt)
            afrag[jt][kt] = *(const bf16x8*)&AT[sig(jt, l) * ROWP + 32*kt + 8*q];

    // Emission A-frag: A_E[m][k] = Bem[sig(jt,m)][k] for k<4 (q==0), else 0.
    bf16x8 afragE[4];
    #pragma unroll
    for (int jt = 0; jt < 4; ++jt) {
        #pragma unroll
        for (int p = 0; p < 8; ++p) afragE[jt][p] = (__bf16)0.f;
        if (q == 0) {
            #pragma unroll
            for (int c = 0; c < 4; ++c)
                afragE[jt][c] = (__bf16)BemS[sig(jt, l)][c];
        }
    }

    // Rv init = I (t=0: R = I), in sig-permuted C layout
    floatx4 Rv[4];
    #pragma unroll
    for (int jt = 0; jt < 4; ++jt)
        #pragma unroll
        for (int r = 0; r < 4; ++r) Rv[jt][r] = IS[sig(jt, 4*q + r)];

    // Compiler barrier: LDS reads above cannot be rematerialized in-loop.
    __asm__ volatile("" ::: "memory");

    const int b = 16*w + l;
    const float* xin = xg + b * (T_ * S_);
    float* llout = out + (size_t)b * T_ * U_ + u;

    const floatx4 z = {0.f, 0.f, 0.f, 0.f};
    floatx4 Ev[4], gv[4];
    float ll = 0.f, sp1 = 0.f, sp2 = 0.f, rsA = 1.0f;

    // Persistent E B-operand fragment: only k<4 (q==0) ever non-zero.
    bf16x8 be;
    #pragma unroll
    for (int p = 0; p < 8; ++p) be[p] = (__bf16)0.f;

    // ---------------- pipeline fill ----------------
    floatx4 x0 = *(const floatx4*)xin;
    floatx4 xA = *(const floatx4*)(xin + S_);       // x_1
    floatx4 xB = *(const floatx4*)(xin + 2 * S_);   // x_2

    {
        if (q == 0) {
            be[0] = (__bf16)x0.x; be[1] = (__bf16)x0.y;
            be[2] = (__bf16)x0.z; be[3] = (__bf16)x0.w;
        }
        #pragma unroll
        for (int jt = 0; jt < 4; ++jt)
            Ev[jt] = __builtin_amdgcn_mfma_f32_16x16x32_bf16(afragE[jt], be, z, 0, 0, 0);
    }

    // ---------------- T-loop: 32-step blocks ----------------
    for (int tb = 0; tb < T_; tb += 32) {
        float hist[8];
        for (int t8 = 0; t8 < 4; ++t8) {         // octet index (not unrolled)
            const bool own = (q == t8);          // this q captures these 8 t's
            #pragma unroll
            for (int k = 0; k < 8; ++k) {
                const int t = tb + 8 * t8 + k;

                // gv_t = Ev_t o Rv_t
                #pragma unroll
                for (int jt = 0; jt < 4; ++jt) gv[jt] = Ev[jt] * Rv[jt];

                // pack b_t = bf16(gv_t)
                bf16x8 bf0, bf1;
                #pragma unroll
                for (int p = 0; p < 4; ++p) {
                    bf0[p]     = (__bf16)gv[0][p];
                    bf0[4 + p] = (__bf16)gv[1][p];
                    bf1[p]     = (__bf16)gv[2][p];
                    bf1[4 + p] = (__bf16)gv[3][p];
                }

                // R_{t+1} = A^T b_t : two independent accumulators + add
                #pragma unroll
                for (int jt = 0; jt < 4; ++jt) {
                    floatx4 a0 = __builtin_amdgcn_mfma_f32_16x16x32_bf16(afrag[jt][0], bf0, z, 0, 0, 0);
                    floatx4 a1 = __builtin_amdgcn_mfma_f32_16x16x32_bf16(afrag[jt][1], bf1, z, 0, 0, 0);
                    Rv[jt] = a0 + a1;
                }

                // ss_t: in-lane + 3 parallel shfls (hidden; consumed next iter)
                floatx4 s4 = (gv[0] + gv[1]) + (gv[2] + gv[3]);
                float p0 = (s4.x + s4.y) + (s4.z + s4.w);
                float a16 = __shfl_xor(p0, 16, 64);
                float a32 = __shfl_xor(p0, 32, 64);
                float a48 = __shfl_xor(p0, 48, 64);
                float ss = (p0 + a16) + (a32 + a48);
                float sg = __logf(ss);
                float rs = __builtin_amdgcn_rcpf(ss);

                // ll_t = ll_{t-1} + sigma_t - sigma_{t-1} + sigma_{t-2}
                ll += sg - sp1 + sp2;
                sp2 = sp1; sp1 = sg;
                if (own) hist[k] = ll;          // v_cndmask into VGPR ring

                // Ev_{t+1}: x_{t+1} scaled by rs_{t-1} (rsA not yet updated)
                if (q == 0) {
                    floatx4 xs = xA * rsA;
                    be[0] = (__bf16)xs.x; be[1] = (__bf16)xs.y;
                    be[2] = (__bf16)xs.z; be[3] = (__bf16)xs.w;
                }
                #pragma unroll
                for (int jt = 0; jt < 4; ++jt)
                    Ev[jt] = __builtin_amdgcn_mfma_f32_16x16x32_bf16(afragE[jt], be, z, 0, 0, 0);
                rsA = rs;

                // x ring: 2 iterations of load slack (only vmem op per iter)
                xA = xB;
                int tp = (t + 3 < T_) ? t + 3 : T_ - 1;
                xB = *(const floatx4*)(xin + tp * S_);
            }
        }
        // flush: lane (q,l) stores t = tb + 8q + k for its batch b
        float* fp = llout + (size_t)(tb + 8 * q) * U_;
        #pragma unroll
        for (int k = 0; k < 8; ++k) fp[(size_t)k * U_] = hist[k];
    }
}

extern "C" void kernel_launch(void* const* d_in, const int* in_sizes, int n_in,
                              void* d_out, int out_size, void* d_ws, size_t ws_size,
                              hipStream_t stream) {
    const float* xg    = (const float*)d_in[0];
    const float* trans = (const float*)d_in[1];
    const float* emis  = (const float*)d_in[2];
    const float* initk = (const float*)d_in[3];
    float* out = (float*)d_out;
    hipLaunchKernelGGL(hmm_fwd_kernel, dim3(U_), dim3(256), 0, stream,
                       xg, trans, emis, initk, out);
}

// Round 7
// 371.311 us; speedup vs baseline: 1.1915x; 1.1915x over previous
//
#include <hip/hip_runtime.h>

// HMM forward scan, one workgroup per unit u. U=256, N=64, S=4, B=64, T=1024.
// Wave w owns batches [16w,16w+16); lane (q=lane>>4,l=lane&15) owns batch
// b=16w+l and the 16 states j = sig(jt, 4q+r).
//
// R4 skeleton (best: 347us): chained R-MFMA, E via K=4 zero-padded MFMA,
// 3-parallel-shfl ss reduce, 1-step-lag normalization (z^2-z+1, stable),
// ll_t = ll_{t-1} + sigma_t - sigma_{t-1} + sigma_{t-2}.
//
// R7 deltas (vmcnt decoupling — in-order retirement means a scattered store
// ahead of a load in the queue stalls every s_waitcnt for that load):
//  1. No per-iter global vmem: ll -> VGPR hist[8] ring (octet q owns 8 t's,
//     1 cndmask/iter), bulk-flushed every 32 steps; x loaded 4-at-a-time
//     into ping-pong register buffers (full 4-iter slack, loads only).
//  2. All-lane be pack: afragE zero columns neutralize k>=4 / q!=0 rows,
//     so the q==0 exec-mask dance is gone.
//  3. Everything else byte-identical to R4 (R5/R6 regressions showed split
//     accumulators and MFMA-reduce are losses).

#define U_ 256
#define N_ 64
#define S_ 4
#define B_ 64
#define T_ 1024
#define ROWP 72

typedef __attribute__((ext_vector_type(8))) __bf16 bf16x8;
typedef __attribute__((ext_vector_type(4))) float floatx4;

__device__ __forceinline__ int sig(int jt, int m) {
    return 32 * (jt >> 1) + 4 * (jt & 1) + 8 * (m >> 2) + (m & 3);
}

__launch_bounds__(256, 1)
__global__ void hmm_fwd_kernel(const float* __restrict__ xg,     // [B][T][S]
                               const float* __restrict__ trans,  // [U][N][N]
                               const float* __restrict__ emis,   // [U][N][S]
                               const float* __restrict__ initk,  // [U][N]
                               float* __restrict__ out)          // [B][T][U]
{
    __shared__ __bf16 AT[N_ * ROWP];
    __shared__ float BemS[N_][S_];
    __shared__ float IS[N_];

    const int bid = blockIdx.x;
    const int u = ((bid & 7) << 5) | (bid >> 3);   // XCD-aware u swizzle
    const int tid = threadIdx.x;
    const int lane = tid & 63;
    const int w = tid >> 6;
    const int q = lane >> 4;
    const int l = lane & 15;

    // ---------------- prologue: softmaxes (one-time) ----------------
    if (tid < 64) {
        const float* rowp = trans + (u * N_ + tid) * N_;
        float v[N_];
        #pragma unroll
        for (int k = 0; k < 16; ++k) {
            floatx4 t4 = *(const floatx4*)(rowp + 4 * k);
            v[4*k] = t4.x; v[4*k+1] = t4.y; v[4*k+2] = t4.z; v[4*k+3] = t4.w;
        }
        float m = v[0];
        #pragma unroll
        for (int j = 1; j < N_; ++j) m = fmaxf(m, v[j]);
        float s = 0.f;
        #pragma unroll
        for (int j = 0; j < N_; ++j) { v[j] = __expf(v[j] - m); s += v[j]; }
        float inv = 1.0f / s;
        #pragma unroll
        for (int j = 0; j < N_; ++j) AT[j * ROWP + tid] = (__bf16)(v[j] * inv);
    } else if (tid < 128) {
        int n = tid - 64;
        floatx4 e4 = *(const floatx4*)(emis + (u * N_ + n) * S_);
        float m = fmaxf(fmaxf(e4.x, e4.y), fmaxf(e4.z, e4.w));
        float a = __expf(e4.x - m), b2 = __expf(e4.y - m);
        float c = __expf(e4.z - m), d = __expf(e4.w - m);
        float inv = 1.0f / (a + b2 + c + d);
        BemS[n][0] = a*inv; BemS[n][1] = b2*inv; BemS[n][2] = c*inv; BemS[n][3] = d*inv;
    } else if (tid < 192) {
        int j = tid - 128;
        float v = initk[u * N_ + j];
        float m = v;
        #pragma unroll
        for (int s = 1; s < 64; s <<= 1) m = fmaxf(m, __shfl_xor(m, s, 64));
        float e = __expf(v - m);
        float ssum = e;
        #pragma unroll
        for (int s = 1; s < 64; s <<= 1) ssum += __shfl_xor(ssum, s, 64);
        IS[j] = e / ssum;
    }
    __syncthreads();

    // ------------- persistent register state -------------
    bf16x8 afrag[4][2];
    #pragma unroll
    for (int jt = 0; jt < 4; ++jt)
        #pragma unroll
        for (int kt = 0; kt < 2; ++kt)
            afrag[jt][kt] = *(const bf16x8*)&AT[sig(jt, l) * ROWP + 32*kt + 8*q];

    // Emission A-frag: A_E[m][k] = Bem[sig(jt,m)][k] for k<4 (q==0), else 0.
    bf16x8 afragE[4];
    #pragma unroll
    for (int jt = 0; jt < 4; ++jt) {
        #pragma unroll
        for (int p = 0; p < 8; ++p) afragE[jt][p] = (__bf16)0.f;
        if (q == 0) {
            #pragma unroll
            for (int c = 0; c < 4; ++c)
                afragE[jt][c] = (__bf16)BemS[sig(jt, l)][c];
        }
    }

    // Rv init = I (t=0: R = I), in sig-permuted C layout
    floatx4 Rv[4];
    #pragma unroll
    for (int jt = 0; jt < 4; ++jt)
        #pragma unroll
        for (int r = 0; r < 4; ++r) Rv[jt][r] = IS[sig(jt, 4*q + r)];

    // Compiler barrier: LDS reads above cannot be rematerialized in-loop.
    __asm__ volatile("" ::: "memory");

    const int b = 16*w + l;
    const float* xin = xg + b * (T_ * S_);
    float* llout = out + (size_t)b * T_ * U_ + u;

    const floatx4 z = {0.f, 0.f, 0.f, 0.f};
    floatx4 Ev[4];
    float ll = 0.f, sp1 = 0.f, sp2 = 0.f, rsA = 1.0f;

    // Persistent E B-operand fragment: k>=4 slots stay zero forever.
    bf16x8 be;
    #pragma unroll
    for (int p = 0; p < 8; ++p) be[p] = (__bf16)0.f;

    // ---------------- pipeline fill ----------------
    floatx4 x0 = *(const floatx4*)xin;
    floatx4 xvA[4], xvB[4];
    #pragma unroll
    for (int i = 0; i < 4; ++i)
        xvA[i] = *(const floatx4*)(xin + (1 + i) * S_);   // x_1..x_4

    {
        // Ev_0 via E-MFMA (kappa_0 = 1); all-lane pack (zeros in A neutralize)
        be[0] = (__bf16)x0.x; be[1] = (__bf16)x0.y;
        be[2] = (__bf16)x0.z; be[3] = (__bf16)x0.w;
        #pragma unroll
        for (int jt = 0; jt < 4; ++jt)
            Ev[jt] = __builtin_amdgcn_mfma_f32_16x16x32_bf16(afragE[jt], be, z, 0, 0, 0);
    }

    float hist[8];
    bool own = false;

    // one HMM step; xsrc = x_{t+1}; slot = t&7 (compile-time after inline)
    auto step = [&](const floatx4& xsrc, int slot) {
        // gv_t = Ev_t o Rv_t
        floatx4 gv[4];
        #pragma unroll
        for (int jt = 0; jt < 4; ++jt) gv[jt] = Ev[jt] * Rv[jt];

        // pack b_t = bf16(gv_t)
        bf16x8 bf0, bf1;
        #pragma unroll
        for (int p = 0; p < 4; ++p) {
            bf0[p]     = (__bf16)gv[0][p];
            bf0[4 + p] = (__bf16)gv[1][p];
            bf1[p]     = (__bf16)gv[2][p];
            bf1[4 + p] = (__bf16)gv[3][p];
        }

        // R_{t+1} = A^T b_t  (chained C accumulation — free on the stream)
        #pragma unroll
        for (int jt = 0; jt < 4; ++jt) {
            floatx4 acc = __builtin_amdgcn_mfma_f32_16x16x32_bf16(afrag[jt][0], bf0, z, 0, 0, 0);
            Rv[jt] = __builtin_amdgcn_mfma_f32_16x16x32_bf16(afrag[jt][1], bf1, acc, 0, 0, 0);
        }

        // ss_t: in-lane + 3 parallel shfls
        floatx4 s4 = (gv[0] + gv[1]) + (gv[2] + gv[3]);
        float p0 = (s4.x + s4.y) + (s4.z + s4.w);
        float a16 = __shfl_xor(p0, 16, 64);
        float a32 = __shfl_xor(p0, 32, 64);
        float a48 = __shfl_xor(p0, 48, 64);
        float ss = (p0 + a16) + (a32 + a48);
        float sg = __logf(ss);
        float rs = __builtin_amdgcn_rcpf(ss);

        // ll_t = ll_{t-1} + sigma_t - sigma_{t-1} + sigma_{t-2}
        ll += sg - sp1 + sp2;
        sp2 = sp1; sp1 = sg;
        hist[slot] = own ? ll : hist[slot];   // v_cndmask into VGPR ring

        // Ev_{t+1}: all-lane pack of x_{t+1} * rs_{t-1}
        floatx4 xs = xsrc * rsA;
        be[0] = (__bf16)xs.x; be[1] = (__bf16)xs.y;
        be[2] = (__bf16)xs.z; be[3] = (__bf16)xs.w;
        #pragma unroll
        for (int jt = 0; jt < 4; ++jt)
            Ev[jt] = __builtin_amdgcn_mfma_f32_16x16x32_bf16(afragE[jt], be, z, 0, 0, 0);
        rsA = rs;
    };

    // ---------------- T-loop: outer step 8, ping-pong x buffers ----------------
    for (int tb = 0; tb < T_; tb += 8) {
        own = (q == ((tb >> 3) & 3));   // octet owner (constant across the 8)

        // load xvB = x_{tb+5..tb+8} (consumed in the second half)
        #pragma unroll
        for (int i = 0; i < 4; ++i) {
            int ti = tb + 5 + i; ti = (ti < T_) ? ti : T_ - 1;
            xvB[i] = *(const floatx4*)(xin + ti * S_);
        }

        step(xvA[0], 0); step(xvA[1], 1); step(xvA[2], 2); step(xvA[3], 3);

        // load xvA = x_{tb+9..tb+12} (consumed next outer iteration)
        #pragma unroll
        for (int i = 0; i < 4; ++i) {
            int ti = tb + 9 + i; ti = (ti < T_) ? ti : T_ - 1;
            xvA[i] = *(const floatx4*)(xin + ti * S_);
        }

        step(xvB[0], 4); step(xvB[1], 5); step(xvB[2], 6); step(xvB[3], 7);

        // flush the completed 32-step block (off-strand bulk stores)
        if ((tb & 24) == 24) {
            float* fp = llout + (size_t)((tb - 24) + 8 * q) * U_;
            #pragma unroll
            for (int k = 0; k < 8; ++k) fp[(size_t)k * U_] = hist[k];
        }
    }
}

extern "C" void kernel_launch(void* const* d_in, const int* in_sizes, int n_in,
                              void* d_out, int out_size, void* d_ws, size_t ws_size,
                              hipStream_t stream) {
    const float* xg    = (const float*)d_in[0];
    const float* trans = (const float*)d_in[1];
    const float* emis  = (const float*)d_in[2];
    const float* initk = (const float*)d_in[3];
    float* out = (float*)d_out;
    hipLaunchKernelGGL(hmm_fwd_kernel, dim3(U_), dim3(256), 0, stream,
                       xg, trans, emis, initk, out);
}

// Round 8
// 361.996 us; speedup vs baseline: 1.2222x; 1.0257x over previous
//
#include <hip/hip_runtime.h>

// HMM forward scan, one workgroup per unit u. U=256, N=64, S=4, B=64, T=1024.
// Wave w owns batches [16w,16w+16); lane (q=lane>>4,l=lane&15) owns batch
// b=16w+l and the 16 states j = sig(jt, 4q+r).
//
// R7 skeleton: chained R-MFMA, E via K=4 zero-padded MFMA, all-lane be pack,
// x ping-pong register buffers, VGPR hist ring + bulk flush.
//
// R8 (in-order-issue fix): with 1 wave/SIMD, any same-step waitcnt is a dead
// SIMD. The ss->log->ll->capture chain was same-step serial (~150+ cyc).
// Now: (1) hist captures RAW ss; log + prefix-sum + ll assembly happen in the
// per-32-step flush:   ll_t = sigma_t + S_{t-2}   (exact telescoping of the
// R4-proven recurrence; S = cumsum(sigma), block carry C, octet-boundary
// sigma_{8o-1} via e1 capture). (2) shfl results of step t-1 are consumed
// (adds+rcp+capture) only AFTER step t's 8 R-MFMAs are issued -> lgkmcnt
// wait covered by a step of MFMA issue. rs lag semantics unchanged
// (x_{t+1}*rs_{t-1}, stable z^2-z+1 magnitude recurrence).

#define U_ 256
#define N_ 64
#define S_ 4
#define B_ 64
#define T_ 1024
#define ROWP 72

typedef __attribute__((ext_vector_type(8))) __bf16 bf16x8;
typedef __attribute__((ext_vector_type(4))) float floatx4;

__device__ __forceinline__ int sig(int jt, int m) {
    return 32 * (jt >> 1) + 4 * (jt & 1) + 8 * (m >> 2) + (m & 3);
}

__launch_bounds__(256, 1)
__global__ void hmm_fwd_kernel(const float* __restrict__ xg,     // [B][T][S]
                               const float* __restrict__ trans,  // [U][N][N]
                               const float* __restrict__ emis,   // [U][N][S]
                               const float* __restrict__ initk,  // [U][N]
                               float* __restrict__ out)          // [B][T][U]
{
    __shared__ __bf16 AT[N_ * ROWP];
    __shared__ float BemS[N_][S_];
    __shared__ float IS[N_];

    const int bid = blockIdx.x;
    const int u = ((bid & 7) << 5) | (bid >> 3);   // XCD-aware u swizzle
    const int tid = threadIdx.x;
    const int lane = tid & 63;
    const int w = tid >> 6;
    const int q = lane >> 4;
    const int l = lane & 15;

    // ---------------- prologue: softmaxes (one-time) ----------------
    if (tid < 64) {
        const float* rowp = trans + (u * N_ + tid) * N_;
        float v[N_];
        #pragma unroll
        for (int k = 0; k < 16; ++k) {
            floatx4 t4 = *(const floatx4*)(rowp + 4 * k);
            v[4*k] = t4.x; v[4*k+1] = t4.y; v[4*k+2] = t4.z; v[4*k+3] = t4.w;
        }
        float m = v[0];
        #pragma unroll
        for (int j = 1; j < N_; ++j) m = fmaxf(m, v[j]);
        float s = 0.f;
        #pragma unroll
        for (int j = 0; j < N_; ++j) { v[j] = __expf(v[j] - m); s += v[j]; }
        float inv = 1.0f / s;
        #pragma unroll
        for (int j = 0; j < N_; ++j) AT[j * ROWP + tid] = (__bf16)(v[j] * inv);
    } else if (tid < 128) {
        int n = tid - 64;
        floatx4 e4 = *(const floatx4*)(emis + (u * N_ + n) * S_);
        float m = fmaxf(fmaxf(e4.x, e4.y), fmaxf(e4.z, e4.w));
        float a = __expf(e4.x - m), b2 = __expf(e4.y - m);
        float c = __expf(e4.z - m), d = __expf(e4.w - m);
        float inv = 1.0f / (a + b2 + c + d);
        BemS[n][0] = a*inv; BemS[n][1] = b2*inv; BemS[n][2] = c*inv; BemS[n][3] = d*inv;
    } else if (tid < 192) {
        int j = tid - 128;
        float v = initk[u * N_ + j];
        float m = v;
        #pragma unroll
        for (int s = 1; s < 64; s <<= 1) m = fmaxf(m, __shfl_xor(m, s, 64));
        float e = __expf(v - m);
        float ssum = e;
        #pragma unroll
        for (int s = 1; s < 64; s <<= 1) ssum += __shfl_xor(ssum, s, 64);
        IS[j] = e / ssum;
    }
    __syncthreads();

    // ------------- persistent register state -------------
    bf16x8 afrag[4][2];
    #pragma unroll
    for (int jt = 0; jt < 4; ++jt)
        #pragma unroll
        for (int kt = 0; kt < 2; ++kt)
            afrag[jt][kt] = *(const bf16x8*)&AT[sig(jt, l) * ROWP + 32*kt + 8*q];

    bf16x8 afragE[4];
    #pragma unroll
    for (int jt = 0; jt < 4; ++jt) {
        #pragma unroll
        for (int p = 0; p < 8; ++p) afragE[jt][p] = (__bf16)0.f;
        if (q == 0) {
            #pragma unroll
            for (int c = 0; c < 4; ++c)
                afragE[jt][c] = (__bf16)BemS[sig(jt, l)][c];
        }
    }

    floatx4 Rv[4];
    #pragma unroll
    for (int jt = 0; jt < 4; ++jt)
        #pragma unroll
        for (int r = 0; r < 4; ++r) Rv[jt][r] = IS[sig(jt, 4*q + r)];

    __asm__ volatile("" ::: "memory");   // pin LDS-sourced state in VGPRs

    const int b = 16*w + l;
    const float* xin = xg + b * (T_ * S_);
    float* llout = out + (size_t)b * T_ * U_ + u;

    const floatx4 z = {0.f, 0.f, 0.f, 0.f};
    floatx4 Ev[4];
    float rsA = 1.0f;                    // rcp(ss_{t-1}); init sigma_{-1}=0

    bf16x8 be;
    #pragma unroll
    for (int p = 0; p < 8; ++p) be[p] = (__bf16)0.f;

    // ---------------- pipeline fill ----------------
    floatx4 x0 = *(const floatx4*)xin;
    floatx4 xvA[4], xvB[4];
    #pragma unroll
    for (int i = 0; i < 4; ++i)
        xvA[i] = *(const floatx4*)(xin + (1 + i) * S_);   // x_1..x_4

    {
        be[0] = (__bf16)x0.x; be[1] = (__bf16)x0.y;
        be[2] = (__bf16)x0.z; be[3] = (__bf16)x0.w;
        #pragma unroll
        for (int jt = 0; jt < 4; ++jt)
            Ev[jt] = __builtin_amdgcn_mfma_f32_16x16x32_bf16(afragE[jt], be, z, 0, 0, 0);
    }

    float hist[8];
    float e1 = 1.0f, pe1 = 1.0f, Cacc = 0.f;
    bool own = false, ownN = false;
    float pp0, pa16, pa32, pa48;         // prev step's un-reduced shfl parts

    // consume step (slot k-1)'s shfl results: ss, rcp, captures.
    auto consume = [&](int kprev) {
        float ss = (pp0 + pa16) + (pa32 + pa48);
        rsA = __builtin_amdgcn_rcpf(ss);
        hist[kprev] = own ? ss : hist[kprev];
        if (kprev == 7) e1 = ownN ? ss : e1;
    };

    // one HMM step; xsrc = x_{t+1}. Issues MFMAs first, then (via caller)
    // the previous step's consume lands after them.
    auto step = [&](const floatx4& xsrc, int slot) {
        // gv_t = Ev_t o Rv_t
        floatx4 gv[4];
        #pragma unroll
        for (int jt = 0; jt < 4; ++jt) gv[jt] = Ev[jt] * Rv[jt];

        // pack b_t
        bf16x8 bf0, bf1;
        #pragma unroll
        for (int p = 0; p < 4; ++p) {
            bf0[p]     = (__bf16)gv[0][p];
            bf0[4 + p] = (__bf16)gv[1][p];
            bf1[p]     = (__bf16)gv[2][p];
            bf1[4 + p] = (__bf16)gv[3][p];
        }

        // R_{t+1} = A^T b_t (chained C accumulation)
        #pragma unroll
        for (int jt = 0; jt < 4; ++jt) {
            floatx4 acc = __builtin_amdgcn_mfma_f32_16x16x32_bf16(afrag[jt][0], bf0, z, 0, 0, 0);
            Rv[jt] = __builtin_amdgcn_mfma_f32_16x16x32_bf16(afrag[jt][1], bf1, acc, 0, 0, 0);
        }

        // consume previous step's shfl results (after MFMA issue)
        if (slot > 0) consume(slot - 1);

        // Ev_{t+1}: x_{t+1} * rs_{t-1}  (rsA just updated by consume)
        floatx4 xs = xsrc * rsA;
        be[0] = (__bf16)xs.x; be[1] = (__bf16)xs.y;
        be[2] = (__bf16)xs.z; be[3] = (__bf16)xs.w;
        #pragma unroll
        for (int jt = 0; jt < 4; ++jt)
            Ev[jt] = __builtin_amdgcn_mfma_f32_16x16x32_bf16(afragE[jt], be, z, 0, 0, 0);

        // issue ss_t reduce last: in-lane adds + 3 parallel shfls
        floatx4 s4 = (gv[0] + gv[1]) + (gv[2] + gv[3]);
        pp0  = (s4.x + s4.y) + (s4.z + s4.w);
        pa16 = __shfl_xor(pp0, 16, 64);
        pa32 = __shfl_xor(pp0, 32, 64);
        pa48 = __shfl_xor(pp0, 48, 64);
    };

    // ---------------- T-loop: outer step 8 ----------------
    for (int tb = 0; tb < T_; tb += 8) {
        const int oct = (tb >> 3) & 3;
        own  = (q == oct);
        ownN = (q == ((oct + 1) & 3));
        if ((tb & 24) == 0) pe1 = e1;   // save prev block's s=31 ss for q==0

        #pragma unroll
        for (int i = 0; i < 4; ++i) {
            int ti = tb + 5 + i; ti = (ti < T_) ? ti : T_ - 1;
            xvB[i] = *(const floatx4*)(xin + ti * S_);
        }

        step(xvA[0], 0); step(xvA[1], 1); step(xvA[2], 2); step(xvA[3], 3);

        #pragma unroll
        for (int i = 0; i < 4; ++i) {
            int ti = tb + 9 + i; ti = (ti < T_) ? ti : T_ - 1;
            xvA[i] = *(const floatx4*)(xin + ti * S_);
        }

        step(xvB[0], 4); step(xvB[1], 5); step(xvB[2], 6); step(xvB[3], 7);

        consume(7);   // tail: once-per-8 exposed wait

        // ---------------- flush completed 32-step block ----------------
        if ((tb & 24) == 24) {
            const int tb0 = tb - 24;
            float sg[8], P[8];
            #pragma unroll
            for (int k = 0; k < 8; ++k) sg[k] = __logf(hist[k]);
            P[0] = sg[0];
            #pragma unroll
            for (int k = 1; k < 8; ++k) P[k] = P[k-1] + sg[k];
            float Loc = P[7];
            float a  = __shfl_xor(Loc, 16, 64);
            float b2 = __shfl_xor(Loc, 32, 64);
            float c  = __shfl_xor(Loc, 48, 64);
            float bc = b2 + c;
            float off = ((q & 1) ? a : 0.f) + ((q & 2) ? bc : 0.f);
            float base = Cacc + off;
            float se1 = __logf((q == 0) ? pe1 : e1);
            float* fp = llout + (size_t)(tb0 + 8 * q) * U_;
            fp[0]          = sg[0] + base - se1;
            fp[U_]         = sg[1] + base;
            #pragma unroll
            for (int k = 2; k < 8; ++k)
                fp[(size_t)k * U_] = sg[k] + base + P[k-2];
            Cacc += Loc + a + bc;
        }
    }
}

extern "C" void kernel_launch(void* const* d_in, const int* in_sizes, int n_in,
                              void* d_out, int out_size, void* d_ws, size_t ws_size,
                              hipStream_t stream) {
    const float* xg    = (const float*)d_in[0];
    const float* trans = (const float*)d_in[1];
    const float* emis  = (const float*)d_in[2];
    const float* initk = (const float*)d_in[3];
    float* out = (float*)d_out;
    hipLaunchKernelGGL(hmm_fwd_kernel, dim3(U_), dim3(256), 0, stream,
                       xg, trans, emis, initk, out);
}